// Round 17
// baseline (126.894 us; speedup 1.0000x reference)
//
#include <hip/hip_runtime.h>

#define HW 4096
#define NE 1024
#define LOSS_OFF 16777216
#define IDX_OFF  16777218
#define MARGIN 0.08f

typedef __attribute__((ext_vector_type(8))) _Float16 half8v;
typedef __attribute__((ext_vector_type(4))) float float4v;

// ws layout (bytes): [0] int flag_count; [64..) int flaglist[65536];
// [262208..) float cnorm[1024]; [266304..) ushort cbh[1024*256]; [790592..) float part[2048]
#define WS_LIST_OFF   64
#define WS_CNORM_OFF  262208
#define WS_CBH_OFF    266304
#define WS_PART_OFF   790592

__device__ __forceinline__ unsigned short f16rne(float f) {
    _Float16 h = (_Float16)f;            // v_cvt_f16_f32, RNE
    return __builtin_bit_cast(unsigned short, h);
}

__device__ __forceinline__ unsigned f16pk(float a, float b) {
    auto h = __builtin_amdgcn_cvt_pkrtz(a, b);   // v_cvt_pkrtz_f16_f32
    return __builtin_bit_cast(unsigned, h);
}

// async global->LDS, 16B per lane; lds base must be wave-uniform (HW adds lane*16)
__device__ __forceinline__ void stage16(const void* g, void* l) {
    __builtin_amdgcn_global_load_lds(
        (const __attribute__((address_space(1))) unsigned*)g,
        (__attribute__((address_space(3))) unsigned*)l, 16, 0, 0);
}

// ---------------- k0: codebook half-norms + fp16 conversion + counter zero ----------------
__global__ __launch_bounds__(256) void k0_prep(const float* __restrict__ cb,
                                               float* __restrict__ cnorm,
                                               unsigned short* __restrict__ cbh,
                                               int* __restrict__ flagcnt) {
    const int tid = threadIdx.x;
    if (blockIdx.x == 0 && tid == 0) *flagcnt = 0;
    const int e = blockIdx.x * 64 + (tid >> 2);
    const int j = tid & 3;
    const float4* src = (const float4*)(cb + (size_t)e * 256 + j * 64);
    unsigned short* dst = cbh + (size_t)e * 256 + j * 64;
    float s = 0.f;
#pragma unroll
    for (int i = 0; i < 16; ++i) {
        float4 v = src[i];
        s += v.x * v.x + v.y * v.y + v.z * v.z + v.w * v.w;
        unsigned p0 = (unsigned)f16rne(v.x) | ((unsigned)f16rne(v.y) << 16);
        unsigned p1 = (unsigned)f16rne(v.z) | ((unsigned)f16rne(v.w) << 16);
        *(uint2*)(dst + i * 4) = make_uint2(p0, p1);
    }
    s += __shfl_xor(s, 1, 64);
    s += __shfl_xor(s, 2, 64);
    if (j == 0) cnorm[e] = 0.5f * s;
}

// ---------------- k1: fp16 MFMA distance + argmin(best1,best2) + flagging ----------------
// r16 structure + three micro-opts: (1) cnorm software-prefetch (cn_cur/cn_next
// rotation hides the per-chunk L2 latency under the MFMA block); (2) s_setprio(1)
// around the MFMA cluster (T5 — 2 drifting blocks/CU give phase diversity);
// (3) final-iteration barrier removed (dead: no restage, cand doesn't alias bufs).
__global__ __launch_bounds__(512, 4) void k1_mfma(const float* __restrict__ z,
                                                  const unsigned short* __restrict__ cbh,
                                                  const float* __restrict__ cnorm,
                                                  float* __restrict__ out_idx,
                                                  int* __restrict__ flagcnt,
                                                  int* __restrict__ flaglist) {
    __shared__ __align__(16) char smem[65536];
    char* bufs = smem;                       // 2 x 16384 chunk buffers (alias zt)
    float* cand1 = (float*)(smem + 49152);   // [128][2] (dead zt space)
    int*   candi = (int*)  (smem + 50176);
    float* cand2 = (float*)(smem + 51200);

    const int tid = threadIdx.x;
    const int lane = tid & 63, wid = tid >> 6;
    const int wx = wid & 1, wy = wid >> 1;
    const int lr = lane & 15, lg = lane >> 4;
    const unsigned bswz = (unsigned)(lr << 4);   // (row&15)<<4 with row%16 == lr

    const int n0 = blockIdx.x * 128;
    const int hw0 = n0 & 4095;
    const float* zb = z + (size_t)(n0 >> 12) * (256 * HW);
    const char* cbh_b = (const char*)cbh;

    // ---- stage z tile transposed [row 0..127][k] fp16 into smem (swizzled) ----
    {
        const int row = tid & 127, kgrp = tid >> 7;
        const unsigned zswz = (unsigned)((row & 15) << 4);
#pragma unroll
        for (int it = 0; it < 8; ++it) {
            int kb = (kgrp + it * 4) * 8;
            float v[8];
#pragma unroll
            for (int q = 0; q < 8; ++q) v[q] = zb[(size_t)(kb + q) * HW + hw0 + row];
            unsigned pk[4];
#pragma unroll
            for (int q = 0; q < 4; ++q) pk[q] = f16pk(v[2*q], v[2*q+1]);
            unsigned scol = (unsigned)(kb * 2) ^ zswz;
            *(int4*)(smem + row * 512 + scol) = make_int4(pk[0], pk[1], pk[2], pk[3]);
        }
    }
    __syncthreads();

    // ---- A-frags: this wave's 32 rows (32*wy..), full K (64 VGPR) ----
    half8v A[2][8];
#pragma unroll
    for (int mi = 0; mi < 2; ++mi)
#pragma unroll
        for (int ks = 0; ks < 8; ++ks)
            A[mi][ks] = *(const half8v*)(smem + (32*wy + 16*mi + lr) * 512
                                              + ((unsigned)(64*ks + 16*lg) ^ bswz));
    __syncthreads();   // zt dead; buffers may be staged over it

    // ---- staging: wave wid covers instrs {2*wid, 2*wid+1} ----
    const int elo_half = lane >> 5;                 // 0/1
    const unsigned col0 = (unsigned)((lane & 31) * 16);

    // stage chunk 0 -> buf0
#pragma unroll
    for (int ii = 0; ii < 2; ++ii) {
        int i = 2 * wid + ii;
        int e_loc = 2 * i + elo_half;
        unsigned col = col0 ^ (unsigned)((e_loc & 15) << 4);
        stage16(cbh_b + (size_t)e_loc * 512 + col, bufs + i * 1024);
    }
    __syncthreads();

    const float* cnp = cnorm + 16 * wx + lr;
    float b1[8], b2[8]; int bi[8];
#pragma unroll
    for (int i = 0; i < 8; ++i) { b1[i] = 1e30f; b2[i] = 1e30f; bi[i] = 0; }

    float cn_cur = cnp[0];
    for (int c = 0; c < 32; ++c) {
        if (c < 31) {
            char* nb = bufs + ((c + 1) & 1) * 16384;
            const size_t ebase = (size_t)(c + 1) * 32;
#pragma unroll
            for (int ii = 0; ii < 2; ++ii) {
                int i = 2 * wid + ii;
                int e_loc = 2 * i + elo_half;
                unsigned col = col0 ^ (unsigned)((e_loc & 15) << 4);
                stage16(cbh_b + (ebase + e_loc) * 512 + col, nb + i * 1024);
            }
        }
        // prefetch next chunk's cnorm early (latency hidden under MFMA block)
        float cn_next = cnp[min(c + 1, 31) * 32];

        const char* bp = bufs + (c & 1) * 16384 + (16 * wx + lr) * 512;
        float4v a0 = {0.f,0.f,0.f,0.f}, a1 = a0;
        __builtin_amdgcn_s_setprio(1);
#pragma unroll
        for (int ks = 0; ks < 8; ++ks) {
            half8v B = *(const half8v*)(bp + ((unsigned)(64*ks + 16*lg) ^ bswz));
            a0 = __builtin_amdgcn_mfma_f32_16x16x32_f16(A[0][ks], B, a0, 0, 0, 0);
            a1 = __builtin_amdgcn_mfma_f32_16x16x32_f16(A[1][ks], B, a1, 0, 0, 0);
        }
        __builtin_amdgcn_s_setprio(0);

        // fold (entries strictly ascend with c -> strict < keeps smallest index)
        const float cn = cn_cur;
        const int e = c * 32 + 16 * wx + lr;
#pragma unroll
        for (int r = 0; r < 4; ++r) {
            float s0 = cn - a0[r];
            b2[r] = fminf(b2[r], fmaxf(b1[r], s0));          // med3 clamp idiom
            if (s0 < b1[r]) { b1[r] = s0; bi[r] = e; }
            float s1 = cn - a1[r];
            b2[4+r] = fminf(b2[4+r], fmaxf(b1[4+r], s1));
            if (s1 < b1[4+r]) { b1[4+r] = s1; bi[4+r] = e; }
        }
        cn_cur = cn_next;

        if (c < 31) __syncthreads();   // next buffer staged + all reads of bp done
    }

    // ---- cross-lane argmin over the 16-lane entry dimension (lr) ----
#pragma unroll
    for (int m = 1; m <= 8; m <<= 1) {
#pragma unroll
        for (int s = 0; s < 8; ++s) {
            float o1 = __shfl_xor(b1[s], m, 64);
            float o2 = __shfl_xor(b2[s], m, 64);
            int   oi = __shfl_xor(bi[s], m, 64);
            float m2 = fminf(fmaxf(b1[s], o1), fminf(b2[s], o2));
            if (o1 < b1[s] || (o1 == b1[s] && oi < bi[s])) { b1[s] = o1; bi[s] = oi; }
            b2[s] = m2;
        }
    }
    if (lr == 0) {
#pragma unroll
        for (int mi = 0; mi < 2; ++mi)
#pragma unroll
            for (int r = 0; r < 4; ++r) {
                int row = 32 * wy + 16 * mi + 4 * lg + r;
                cand1[row * 2 + wx] = b1[mi * 4 + r];
                cand2[row * 2 + wx] = b2[mi * 4 + r];
                candi[row * 2 + wx] = bi[mi * 4 + r];
            }
    }
    __syncthreads();
    if (tid < 128) {
        float s1a = cand1[tid * 2], s1b = cand1[tid * 2 + 1];
        int   ia = candi[tid * 2],  ib = candi[tid * 2 + 1];
        float s2 = fminf(fminf(cand2[tid * 2], cand2[tid * 2 + 1]), fmaxf(s1a, s1b));
        float s1; int iw;
        if (s1b < s1a || (s1b == s1a && ib < ia)) { s1 = s1b; iw = ib; }
        else { s1 = s1a; iw = ia; }
        out_idx[n0 + tid] = (float)iw;
        if (s2 - s1 < MARGIN) {
            int p = atomicAdd(flagcnt, 1);
            flaglist[p] = n0 + tid;
        }
    }
}

// ---------------- k1b: exact fp32 re-argmin, 4 rows/block, 4-lane entry groups ----
__global__ __launch_bounds__(256) void k1b_refine(const float* __restrict__ z,
                                                  const float* __restrict__ cb,
                                                  const float* __restrict__ cnorm,
                                                  const int* __restrict__ flagcnt,
                                                  const int* __restrict__ flaglist,
                                                  float* __restrict__ out_idx) {
    __shared__ float zr[4][260];
    __shared__ int   rows[4];
    __shared__ float wb[4][4];
    __shared__ int   wi[4][4];
    const int tid = threadIdx.x;
    const int lane = tid & 63, w = tid >> 6;
    const int gid = tid >> 2, j = tid & 3;     // entry group 0..63, quarter 0..3
    const int count = *flagcnt;
    for (int base = blockIdx.x * 4; base < count; base += gridDim.x * 4) {
        const int nr = min(4, count - base);
        __syncthreads();   // protect zr/rows/wb from previous iteration
        if (tid < nr) rows[tid] = flaglist[base + tid];
        __syncthreads();
        for (int r = 0; r < nr; ++r) {
            const int n = rows[r];
            zr[r][tid] = z[((size_t)(n >> 12) * 256 + tid) * HW + (n & 4095)];
        }
        __syncthreads();

        float acc[16][4];
#pragma unroll
        for (int p = 0; p < 16; ++p)
#pragma unroll
            for (int r = 0; r < 4; ++r) acc[p][r] = 0.f;

        const char* cbase = (const char*)cb + (size_t)gid * 1024 + j * 16;
#pragma unroll 2
        for (int q = 0; q < 16; ++q) {
            float4 zv[4];
#pragma unroll
            for (int r = 0; r < 4; ++r) zv[r] = *(const float4*)(&zr[r][q * 16 + j * 4]);
#pragma unroll
            for (int p = 0; p < 16; ++p) {
                float4 c = *(const float4*)(cbase + (size_t)p * 65536 + q * 64);
#pragma unroll
                for (int r = 0; r < 4; ++r) {
                    float a = acc[p][r];
                    a = fmaf(zv[r].x, c.x, a);
                    a = fmaf(zv[r].y, c.y, a);
                    a = fmaf(zv[r].z, c.z, a);
                    a = fmaf(zv[r].w, c.w, a);
                    acc[p][r] = a;
                }
            }
        }

        float best[4]; int bidx[4];
#pragma unroll
        for (int r = 0; r < 4; ++r) { best[r] = 1e30f; bidx[r] = 0; }
#pragma unroll
        for (int p = 0; p < 16; ++p) {
            const int e = p * 64 + gid;
            const float cn = cnorm[e];
#pragma unroll
            for (int r = 0; r < 4; ++r) {
                float d = acc[p][r];
                d += __shfl_xor(d, 1, 64);
                d += __shfl_xor(d, 2, 64);
                float s = cn - d;
                if (s < best[r]) { best[r] = s; bidx[r] = e; }
            }
        }
#pragma unroll
        for (int m = 1; m <= 32; m <<= 1) {
#pragma unroll
            for (int r = 0; r < 4; ++r) {
                float ob = __shfl_xor(best[r], m, 64);
                int   oi = __shfl_xor(bidx[r], m, 64);
                if (ob < best[r] || (ob == best[r] && oi < bidx[r])) { best[r] = ob; bidx[r] = oi; }
            }
        }
        if (lane == 0) {
#pragma unroll
            for (int r = 0; r < 4; ++r) { wb[w][r] = best[r]; wi[w][r] = bidx[r]; }
        }
        __syncthreads();
        if (tid < nr) {
            float bb = wb[0][tid]; int ii = wi[0][tid];
#pragma unroll
            for (int q = 1; q < 4; ++q)
                if (wb[q][tid] < bb || (wb[q][tid] == bb && wi[q][tid] < ii)) { bb = wb[q][tid]; ii = wi[q][tid]; }
            out_idx[rows[tid]] = (float)ii;
        }
        __syncthreads();
    }
}

// ---------------- k2: LDS-staged gather z_q + fused loss partials ----------------
__global__ __launch_bounds__(256) void k2_scatter(const float* __restrict__ z,
                                                  const float* __restrict__ cb,
                                                  const float* __restrict__ idxf,
                                                  float* __restrict__ zq,
                                                  float* __restrict__ part) {
    __shared__ float cbrow[32][257];
    __shared__ int   earr[32];
    __shared__ float ls[4];
    const int tid = threadIdx.x;
    const int b = blockIdx.x >> 7;                 // 16 batches x 128 groups
    const int hw0 = (blockIdx.x & 127) * 32;

    if (tid < 32) earr[tid] = (int)idxf[b * 4096 + hw0 + tid];
    __syncthreads();
    {
        const int r = tid >> 3, qd = tid & 7;      // row 0..31, 8 threads/row
        const float* src = cb + (size_t)earr[r] * 256 + qd * 4;
#pragma unroll
        for (int k = 0; k < 8; ++k) {
            float4 v = *(const float4*)(src + k * 32);
            *(float4*)(&cbrow[r][qd * 4 + k * 32]) = v;
        }
    }
    __syncthreads();

    const int hw = tid & 31, cq = tid >> 5;        // cq 0..7
    const size_t zbase = ((size_t)b * 256) * 4096 + hw0 + hw;
    float lsum = 0.f;
#pragma unroll 8
    for (int pass = 0; pass < 32; ++pass) {
        const int c = pass * 8 + cq;
        const size_t flat = zbase + (size_t)c * 4096;
        float q = cbrow[hw][c];
        zq[flat] = q;
        float d = q - z[flat];
        lsum = fmaf(d, d, lsum);
    }
#pragma unroll
    for (int m = 32; m >= 1; m >>= 1) lsum += __shfl_down(lsum, m, 64);
    const int lane = tid & 63, w = tid >> 6;
    if (lane == 0) ls[w] = lsum;
    __syncthreads();
    if (tid == 0) part[blockIdx.x] = ls[0] + ls[1] + ls[2] + ls[3];
}

// ---------------- k3: final loss reduce + constants ----------------
__global__ __launch_bounds__(256) void k3_final(const float* __restrict__ part,
                                                float* __restrict__ dout) {
    __shared__ float ls[4];
    float s = 0.f;
#pragma unroll
    for (int it = 0; it < 8; ++it) s += part[threadIdx.x + it * 256];
#pragma unroll
    for (int m = 32; m >= 1; m >>= 1) s += __shfl_down(s, m, 64);
    int lane = threadIdx.x & 63, w = threadIdx.x >> 6;
    if (lane == 0) ls[w] = s;
    __syncthreads();
    if (threadIdx.x == 0) {
        float total = ls[0] + ls[1] + ls[2] + ls[3];
        dout[LOSS_OFF]     = total / 16777216.0f;
        dout[LOSS_OFF + 1] = 0.0f;
    }
}

extern "C" void kernel_launch(void* const* d_in, const int* in_sizes, int n_in,
                              void* d_out, int out_size, void* d_ws, size_t ws_size,
                              hipStream_t stream) {
    const float* z  = (const float*)d_in[0];
    const float* cb = (const float*)d_in[1];
    float* out = (float*)d_out;
    char* ws = (char*)d_ws;

    int*            flagcnt  = (int*)ws;
    int*            flaglist = (int*)(ws + WS_LIST_OFF);
    float*          cnorm    = (float*)(ws + WS_CNORM_OFF);
    unsigned short* cbh      = (unsigned short*)(ws + WS_CBH_OFF);
    float*          part     = (float*)(ws + WS_PART_OFF);

    hipLaunchKernelGGL(k0_prep,   dim3(16),   dim3(256), 0, stream, cb, cnorm, cbh, flagcnt);
    hipLaunchKernelGGL(k1_mfma,   dim3(512),  dim3(512), 0, stream,
                       z, cbh, cnorm, out + IDX_OFF, flagcnt, flaglist);
    hipLaunchKernelGGL(k1b_refine, dim3(2048), dim3(256), 0, stream,
                       z, cb, cnorm, flagcnt, flaglist, out + IDX_OFF);
    hipLaunchKernelGGL(k2_scatter, dim3(2048), dim3(256), 0, stream,
                       z, cb, out + IDX_OFF, out, part);
    hipLaunchKernelGGL(k3_final,  dim3(1),    dim3(256), 0, stream, part, out);
}

// Round 18
// 123.048 us; speedup vs baseline: 1.0312x; 1.0312x over previous
//
#include <hip/hip_runtime.h>

#define HW 4096
#define NE 1024
#define LOSS_OFF 16777216
#define IDX_OFF  16777218
#define MARGIN 0.08f

typedef __attribute__((ext_vector_type(8))) _Float16 half8v;
typedef __attribute__((ext_vector_type(4))) float float4v;

// ws layout (bytes): [0] int flag_count; [64..) int flaglist[65536];
// [262208..) float cnorm[1024]; [266304..) ushort cbh[1024*256]; [790592..) float part[2048]
#define WS_LIST_OFF   64
#define WS_CNORM_OFF  262208
#define WS_CBH_OFF    266304
#define WS_PART_OFF   790592

__device__ __forceinline__ unsigned short f16rne(float f) {
    _Float16 h = (_Float16)f;            // v_cvt_f16_f32, RNE
    return __builtin_bit_cast(unsigned short, h);
}

__device__ __forceinline__ unsigned f16pk(float a, float b) {
    auto h = __builtin_amdgcn_cvt_pkrtz(a, b);   // v_cvt_pkrtz_f16_f32
    return __builtin_bit_cast(unsigned, h);
}

// async global->LDS, 16B per lane; lds base must be wave-uniform (HW adds lane*16)
__device__ __forceinline__ void stage16(const void* g, void* l) {
    __builtin_amdgcn_global_load_lds(
        (const __attribute__((address_space(1))) unsigned*)g,
        (__attribute__((address_space(3))) unsigned*)l, 16, 0, 0);
}

// ---------------- k0: codebook half-norms + fp16 conversion + counter zero ----------------
__global__ __launch_bounds__(256) void k0_prep(const float* __restrict__ cb,
                                               float* __restrict__ cnorm,
                                               unsigned short* __restrict__ cbh,
                                               int* __restrict__ flagcnt) {
    const int tid = threadIdx.x;
    if (blockIdx.x == 0 && tid == 0) *flagcnt = 0;
    const int e = blockIdx.x * 64 + (tid >> 2);
    const int j = tid & 3;
    const float4* src = (const float4*)(cb + (size_t)e * 256 + j * 64);
    unsigned short* dst = cbh + (size_t)e * 256 + j * 64;
    float s = 0.f;
#pragma unroll
    for (int i = 0; i < 16; ++i) {
        float4 v = src[i];
        s += v.x * v.x + v.y * v.y + v.z * v.z + v.w * v.w;
        unsigned p0 = (unsigned)f16rne(v.x) | ((unsigned)f16rne(v.y) << 16);
        unsigned p1 = (unsigned)f16rne(v.z) | ((unsigned)f16rne(v.w) << 16);
        *(uint2*)(dst + i * 4) = make_uint2(p0, p1);
    }
    s += __shfl_xor(s, 1, 64);
    s += __shfl_xor(s, 2, 64);
    if (j == 0) cnorm[e] = 0.5f * s;
}

// ---------------- k1: fp16 MFMA distance + argmin(best1,best2) + flagging ----------------
// Best-measured structure (r16, 123.6 µs total): 512 threads (8 waves), 128 rows x
// 1024 entries per block, grid 512 = exactly 2 blocks/CU all-resident. Codebook
// staged once per block per chunk (2x16KB double buffer); zt 64KB transposed z,
// first 32KB reused as buffers, dead zt space holds cand arrays.
__global__ __launch_bounds__(512, 4) void k1_mfma(const float* __restrict__ z,
                                                  const unsigned short* __restrict__ cbh,
                                                  const float* __restrict__ cnorm,
                                                  float* __restrict__ out_idx,
                                                  int* __restrict__ flagcnt,
                                                  int* __restrict__ flaglist) {
    __shared__ __align__(16) char smem[65536];
    char* bufs = smem;                       // 2 x 16384 chunk buffers (alias zt)
    float* cand1 = (float*)(smem + 49152);   // [128][2] (dead zt space)
    int*   candi = (int*)  (smem + 50176);
    float* cand2 = (float*)(smem + 51200);

    const int tid = threadIdx.x;
    const int lane = tid & 63, wid = tid >> 6;
    const int wx = wid & 1, wy = wid >> 1;
    const int lr = lane & 15, lg = lane >> 4;
    const unsigned bswz = (unsigned)(lr << 4);   // (row&15)<<4 with row%16 == lr

    const int n0 = blockIdx.x * 128;
    const int hw0 = n0 & 4095;
    const float* zb = z + (size_t)(n0 >> 12) * (256 * HW);
    const char* cbh_b = (const char*)cbh;

    // ---- stage z tile transposed [row 0..127][k] fp16 into smem (swizzled) ----
    {
        const int row = tid & 127, kgrp = tid >> 7;
        const unsigned zswz = (unsigned)((row & 15) << 4);
#pragma unroll
        for (int it = 0; it < 8; ++it) {
            int kb = (kgrp + it * 4) * 8;
            float v[8];
#pragma unroll
            for (int q = 0; q < 8; ++q) v[q] = zb[(size_t)(kb + q) * HW + hw0 + row];
            unsigned pk[4];
#pragma unroll
            for (int q = 0; q < 4; ++q) pk[q] = f16pk(v[2*q], v[2*q+1]);
            unsigned scol = (unsigned)(kb * 2) ^ zswz;
            *(int4*)(smem + row * 512 + scol) = make_int4(pk[0], pk[1], pk[2], pk[3]);
        }
    }
    __syncthreads();

    // ---- A-frags: this wave's 32 rows (32*wy..), full K (64 VGPR) ----
    half8v A[2][8];
#pragma unroll
    for (int mi = 0; mi < 2; ++mi)
#pragma unroll
        for (int ks = 0; ks < 8; ++ks)
            A[mi][ks] = *(const half8v*)(smem + (32*wy + 16*mi + lr) * 512
                                              + ((unsigned)(64*ks + 16*lg) ^ bswz));
    __syncthreads();   // zt dead; buffers may be staged over it

    // ---- staging: wave wid covers instrs {2*wid, 2*wid+1} ----
    const int elo_half = lane >> 5;                 // 0/1
    const unsigned col0 = (unsigned)((lane & 31) * 16);

    // stage chunk 0 -> buf0
#pragma unroll
    for (int ii = 0; ii < 2; ++ii) {
        int i = 2 * wid + ii;
        int e_loc = 2 * i + elo_half;
        unsigned col = col0 ^ (unsigned)((e_loc & 15) << 4);
        stage16(cbh_b + (size_t)e_loc * 512 + col, bufs + i * 1024);
    }
    __syncthreads();

    const float* cnp = cnorm + 16 * wx + lr;
    float b1[8], b2[8]; int bi[8];
#pragma unroll
    for (int i = 0; i < 8; ++i) { b1[i] = 1e30f; b2[i] = 1e30f; bi[i] = 0; }

    for (int c = 0; c < 32; ++c) {
        if (c < 31) {
            char* nb = bufs + ((c + 1) & 1) * 16384;
            const size_t ebase = (size_t)(c + 1) * 32;
#pragma unroll
            for (int ii = 0; ii < 2; ++ii) {
                int i = 2 * wid + ii;
                int e_loc = 2 * i + elo_half;
                unsigned col = col0 ^ (unsigned)((e_loc & 15) << 4);
                stage16(cbh_b + (ebase + e_loc) * 512 + col, nb + i * 1024);
            }
        }

        const char* bp = bufs + (c & 1) * 16384 + (16 * wx + lr) * 512;
        float4v a0 = {0.f,0.f,0.f,0.f}, a1 = a0;
#pragma unroll
        for (int ks = 0; ks < 8; ++ks) {
            half8v B = *(const half8v*)(bp + ((unsigned)(64*ks + 16*lg) ^ bswz));
            a0 = __builtin_amdgcn_mfma_f32_16x16x32_f16(A[0][ks], B, a0, 0, 0, 0);
            a1 = __builtin_amdgcn_mfma_f32_16x16x32_f16(A[1][ks], B, a1, 0, 0, 0);
        }

        const float cn = cnp[c * 32];
        const int e = c * 32 + 16 * wx + lr;
#pragma unroll
        for (int r = 0; r < 4; ++r) {
            float s0 = cn - a0[r];
            b2[r] = fminf(b2[r], fmaxf(b1[r], s0));          // med3 clamp idiom
            if (s0 < b1[r]) { b1[r] = s0; bi[r] = e; }
            float s1 = cn - a1[r];
            b2[4+r] = fminf(b2[4+r], fmaxf(b1[4+r], s1));
            if (s1 < b1[4+r]) { b1[4+r] = s1; bi[4+r] = e; }
        }

        __syncthreads();   // next buffer staged + all reads of bp done
    }

    // ---- cross-lane argmin over the 16-lane entry dimension (lr) ----
#pragma unroll
    for (int m = 1; m <= 8; m <<= 1) {
#pragma unroll
        for (int s = 0; s < 8; ++s) {
            float o1 = __shfl_xor(b1[s], m, 64);
            float o2 = __shfl_xor(b2[s], m, 64);
            int   oi = __shfl_xor(bi[s], m, 64);
            float m2 = fminf(fmaxf(b1[s], o1), fminf(b2[s], o2));
            if (o1 < b1[s] || (o1 == b1[s] && oi < bi[s])) { b1[s] = o1; bi[s] = oi; }
            b2[s] = m2;
        }
    }
    if (lr == 0) {
#pragma unroll
        for (int mi = 0; mi < 2; ++mi)
#pragma unroll
            for (int r = 0; r < 4; ++r) {
                int row = 32 * wy + 16 * mi + 4 * lg + r;
                cand1[row * 2 + wx] = b1[mi * 4 + r];
                cand2[row * 2 + wx] = b2[mi * 4 + r];
                candi[row * 2 + wx] = bi[mi * 4 + r];
            }
    }
    __syncthreads();
    if (tid < 128) {
        float s1a = cand1[tid * 2], s1b = cand1[tid * 2 + 1];
        int   ia = candi[tid * 2],  ib = candi[tid * 2 + 1];
        float s2 = fminf(fminf(cand2[tid * 2], cand2[tid * 2 + 1]), fmaxf(s1a, s1b));
        float s1; int iw;
        if (s1b < s1a || (s1b == s1a && ib < ia)) { s1 = s1b; iw = ib; }
        else { s1 = s1a; iw = ia; }
        out_idx[n0 + tid] = (float)iw;
        if (s2 - s1 < MARGIN) {
            int p = atomicAdd(flagcnt, 1);
            flaglist[p] = n0 + tid;
        }
    }
}

// ---------------- k1b: exact fp32 re-argmin, 4 rows/block, 4-lane entry groups ----
__global__ __launch_bounds__(256) void k1b_refine(const float* __restrict__ z,
                                                  const float* __restrict__ cb,
                                                  const float* __restrict__ cnorm,
                                                  const int* __restrict__ flagcnt,
                                                  const int* __restrict__ flaglist,
                                                  float* __restrict__ out_idx) {
    __shared__ float zr[4][260];
    __shared__ int   rows[4];
    __shared__ float wb[4][4];
    __shared__ int   wi[4][4];
    const int tid = threadIdx.x;
    const int lane = tid & 63, w = tid >> 6;
    const int gid = tid >> 2, j = tid & 3;     // entry group 0..63, quarter 0..3
    const int count = *flagcnt;
    for (int base = blockIdx.x * 4; base < count; base += gridDim.x * 4) {
        const int nr = min(4, count - base);
        __syncthreads();   // protect zr/rows/wb from previous iteration
        if (tid < nr) rows[tid] = flaglist[base + tid];
        __syncthreads();
        for (int r = 0; r < nr; ++r) {
            const int n = rows[r];
            zr[r][tid] = z[((size_t)(n >> 12) * 256 + tid) * HW + (n & 4095)];
        }
        __syncthreads();

        float acc[16][4];
#pragma unroll
        for (int p = 0; p < 16; ++p)
#pragma unroll
            for (int r = 0; r < 4; ++r) acc[p][r] = 0.f;

        const char* cbase = (const char*)cb + (size_t)gid * 1024 + j * 16;
#pragma unroll 2
        for (int q = 0; q < 16; ++q) {
            float4 zv[4];
#pragma unroll
            for (int r = 0; r < 4; ++r) zv[r] = *(const float4*)(&zr[r][q * 16 + j * 4]);
#pragma unroll
            for (int p = 0; p < 16; ++p) {
                float4 c = *(const float4*)(cbase + (size_t)p * 65536 + q * 64);
#pragma unroll
                for (int r = 0; r < 4; ++r) {
                    float a = acc[p][r];
                    a = fmaf(zv[r].x, c.x, a);
                    a = fmaf(zv[r].y, c.y, a);
                    a = fmaf(zv[r].z, c.z, a);
                    a = fmaf(zv[r].w, c.w, a);
                    acc[p][r] = a;
                }
            }
        }

        float best[4]; int bidx[4];
#pragma unroll
        for (int r = 0; r < 4; ++r) { best[r] = 1e30f; bidx[r] = 0; }
#pragma unroll
        for (int p = 0; p < 16; ++p) {
            const int e = p * 64 + gid;
            const float cn = cnorm[e];
#pragma unroll
            for (int r = 0; r < 4; ++r) {
                float d = acc[p][r];
                d += __shfl_xor(d, 1, 64);
                d += __shfl_xor(d, 2, 64);
                float s = cn - d;
                if (s < best[r]) { best[r] = s; bidx[r] = e; }
            }
        }
#pragma unroll
        for (int m = 1; m <= 32; m <<= 1) {
#pragma unroll
            for (int r = 0; r < 4; ++r) {
                float ob = __shfl_xor(best[r], m, 64);
                int   oi = __shfl_xor(bidx[r], m, 64);
                if (ob < best[r] || (ob == best[r] && oi < bidx[r])) { best[r] = ob; bidx[r] = oi; }
            }
        }
        if (lane == 0) {
#pragma unroll
            for (int r = 0; r < 4; ++r) { wb[w][r] = best[r]; wi[w][r] = bidx[r]; }
        }
        __syncthreads();
        if (tid < nr) {
            float bb = wb[0][tid]; int ii = wi[0][tid];
#pragma unroll
            for (int q = 1; q < 4; ++q)
                if (wb[q][tid] < bb || (wb[q][tid] == bb && wi[q][tid] < ii)) { bb = wb[q][tid]; ii = wi[q][tid]; }
            out_idx[rows[tid]] = (float)ii;
        }
        __syncthreads();
    }
}

// ---------------- k2: LDS-staged gather z_q + fused loss partials ----------------
__global__ __launch_bounds__(256) void k2_scatter(const float* __restrict__ z,
                                                  const float* __restrict__ cb,
                                                  const float* __restrict__ idxf,
                                                  float* __restrict__ zq,
                                                  float* __restrict__ part) {
    __shared__ float cbrow[32][257];
    __shared__ int   earr[32];
    __shared__ float ls[4];
    const int tid = threadIdx.x;
    const int b = blockIdx.x >> 7;                 // 16 batches x 128 groups
    const int hw0 = (blockIdx.x & 127) * 32;

    if (tid < 32) earr[tid] = (int)idxf[b * 4096 + hw0 + tid];
    __syncthreads();
    {
        const int r = tid >> 3, qd = tid & 7;      // row 0..31, 8 threads/row
        const float* src = cb + (size_t)earr[r] * 256 + qd * 4;
#pragma unroll
        for (int k = 0; k < 8; ++k) {
            float4 v = *(const float4*)(src + k * 32);
            *(float4*)(&cbrow[r][qd * 4 + k * 32]) = v;
        }
    }
    __syncthreads();

    const int hw = tid & 31, cq = tid >> 5;        // cq 0..7
    const size_t zbase = ((size_t)b * 256) * 4096 + hw0 + hw;
    float lsum = 0.f;
#pragma unroll 8
    for (int pass = 0; pass < 32; ++pass) {
        const int c = pass * 8 + cq;
        const size_t flat = zbase + (size_t)c * 4096;
        float q = cbrow[hw][c];
        zq[flat] = q;
        float d = q - z[flat];
        lsum = fmaf(d, d, lsum);
    }
#pragma unroll
    for (int m = 32; m >= 1; m >>= 1) lsum += __shfl_down(lsum, m, 64);
    const int lane = tid & 63, w = tid >> 6;
    if (lane == 0) ls[w] = lsum;
    __syncthreads();
    if (tid == 0) part[blockIdx.x] = ls[0] + ls[1] + ls[2] + ls[3];
}

// ---------------- k3: final loss reduce + constants ----------------
__global__ __launch_bounds__(256) void k3_final(const float* __restrict__ part,
                                                float* __restrict__ dout) {
    __shared__ float ls[4];
    float s = 0.f;
#pragma unroll
    for (int it = 0; it < 8; ++it) s += part[threadIdx.x + it * 256];
#pragma unroll
    for (int m = 32; m >= 1; m >>= 1) s += __shfl_down(s, m, 64);
    int lane = threadIdx.x & 63, w = threadIdx.x >> 6;
    if (lane == 0) ls[w] = s;
    __syncthreads();
    if (threadIdx.x == 0) {
        float total = ls[0] + ls[1] + ls[2] + ls[3];
        dout[LOSS_OFF]     = total / 16777216.0f;
        dout[LOSS_OFF + 1] = 0.0f;
    }
}

extern "C" void kernel_launch(void* const* d_in, const int* in_sizes, int n_in,
                              void* d_out, int out_size, void* d_ws, size_t ws_size,
                              hipStream_t stream) {
    const float* z  = (const float*)d_in[0];
    const float* cb = (const float*)d_in[1];
    float* out = (float*)d_out;
    char* ws = (char*)d_ws;

    int*            flagcnt  = (int*)ws;
    int*            flaglist = (int*)(ws + WS_LIST_OFF);
    float*          cnorm    = (float*)(ws + WS_CNORM_OFF);
    unsigned short* cbh      = (unsigned short*)(ws + WS_CBH_OFF);
    float*          part     = (float*)(ws + WS_PART_OFF);

    hipLaunchKernelGGL(k0_prep,   dim3(16),   dim3(256), 0, stream, cb, cnorm, cbh, flagcnt);
    hipLaunchKernelGGL(k1_mfma,   dim3(512),  dim3(512), 0, stream,
                       z, cbh, cnorm, out + IDX_OFF, flagcnt, flaglist);
    hipLaunchKernelGGL(k1b_refine, dim3(2048), dim3(256), 0, stream,
                       z, cb, cnorm, flagcnt, flaglist, out + IDX_OFF);
    hipLaunchKernelGGL(k2_scatter, dim3(2048), dim3(256), 0, stream,
                       z, cb, out + IDX_OFF, out, part);
    hipLaunchKernelGGL(k3_final,  dim3(1),    dim3(256), 0, stream, part, out);
}